// Round 8
// baseline (868.424 us; speedup 1.0000x reference)
//
#include <hip/hip_runtime.h>
#include <hip/hip_bf16.h>
#include <cstddef>
#include <cstdint>
#include <cstring>

// Problem constants: B=4, T=2048, C=1024, NH=16, hs=64, M = B*T = 8192
#define B_DIM 4
#define T_DIM 2048
#define C_DIM 1024
#define NHEAD 16
#define HS    64

// softmax scale folded into Q at projection: exp(s/8) = exp2(s * 0.125*log2e)
#define QSCALE 0.1803368801111204f

typedef __attribute__((ext_vector_type(8))) short short8;   // 8 bf16 (MFMA A/B frag)
typedef __attribute__((ext_vector_type(4))) short short4v;  // 4 bf16 = 8B
typedef __attribute__((ext_vector_type(4))) float f32x4;    // MFMA C/D frag

__device__ __forceinline__ short f2bf(float x) {
    __hip_bfloat16 b = __float2bfloat16(x);   // RNE
    return *reinterpret_cast<short*>(&b);
}
__device__ __forceinline__ float b2f(short s) {
    unsigned u = ((unsigned)(unsigned short)s) << 16;
    float f; __builtin_memcpy(&f, &u, 4); return f;
}

// async global->LDS, 16B per lane; LDS dest is wave-uniform base + lane*16.
__device__ __forceinline__ void load_lds16(const void* g, void* l) {
    __builtin_amdgcn_global_load_lds(
        (const __attribute__((address_space(1))) void*)(g),
        (__attribute__((address_space(3))) void*)(l),
        16, 0, 0);
}

// ---------------------------------------------------------------------------
// Fused casts: y=0 -> x (4096 blocks), y=1..4 -> Wq/Wk/Wv/Wo (512 blocks used)
// ---------------------------------------------------------------------------
__global__ __launch_bounds__(256) void cast_all(
    const float* __restrict__ x,
    const float* __restrict__ Wq, const float* __restrict__ Wk,
    const float* __restrict__ Wv, const float* __restrict__ Wo,
    short* __restrict__ xb, short* __restrict__ W3b, short* __restrict__ Wob,
    int xn8, int wn8)
{
    int i = blockIdx.x * 256 + threadIdx.x;
    const float* in; short* out; int n8;
    switch (blockIdx.y) {
        case 0:  in = x;  out = xb;             n8 = xn8; break;
        case 1:  in = Wq; out = W3b;            n8 = wn8; break;
        case 2:  in = Wk; out = W3b + (size_t)wn8 * 8;      n8 = wn8; break;
        case 3:  in = Wv; out = W3b + (size_t)wn8 * 16;     n8 = wn8; break;
        default: in = Wo; out = Wob;            n8 = wn8; break;
    }
    if (i >= n8) return;
    const float4* p = (const float4*)in + (size_t)i * 2;
    float4 a = p[0], b = p[1];
    short8 o;
    o[0]=f2bf(a.x); o[1]=f2bf(a.y); o[2]=f2bf(a.z); o[3]=f2bf(a.w);
    o[4]=f2bf(b.x); o[5]=f2bf(b.y); o[6]=f2bf(b.z); o[7]=f2bf(b.w);
    *((short8*)out + i) = o;
}

// ---------------------------------------------------------------------------
// MFMA GEMM: C[M,N] = A[M,K] @ B[N,K]^T, bf16 in, fp32 accumulate.
// 128x128 tile, BK=32, 4 waves (2x2), 16x16x32 MFMA, global_load_lds w=16,
// XOR-swizzled LDS (chunk q of row m at slot m*4 + (q ^ ((m>>1)&3))).
// MODE 0: plain fp32 C store.
// MODE 2: fused QKV epilogue -- cols [0,1024) -> Qp (scaled by qscale, bf16),
//         [1024,2048) -> Kp (bf16), [2048,3072) -> Vtp TRANSPOSED to
//         [B*NH][HS][T] (bf16). Kills the separate transpose pass.
// ---------------------------------------------------------------------------
#define BM 128
#define BN 128
#define BK 32

template<int MODE>
__global__ __launch_bounds__(256) void gemm_bt_mfma(
    const short* __restrict__ A,
    const short* __restrict__ Bm,
    float* __restrict__ Cf,
    short* __restrict__ Qp, short* __restrict__ Kp, short* __restrict__ Vtp,
    int M, int N, int K, float qscale)
{
    __shared__ __align__(16) short smem[8192];   // As 8KB | Bs 8KB
    short* As = smem;
    short* Bs = smem + 4096;

    const int m0 = blockIdx.y * BM;
    const int n0 = blockIdx.x * BN;
    const int t    = threadIdx.x;
    const int w    = t >> 6;
    const int lane = t & 63;
    const int l16  = lane & 15;
    const int quad = lane >> 4;
    const int wm   = w >> 1;
    const int wn   = w & 1;

    const int mS0 = t >> 2;
    const int qS  = (t & 3) ^ ((t >> 3) & 3);
    const short* aG0 = A  + (size_t)(m0 + mS0)      * K + qS * 8;
    const short* aG1 = A  + (size_t)(m0 + mS0 + 64) * K + qS * 8;
    const short* bG0 = Bm + (size_t)(n0 + mS0)      * K + qS * 8;
    const short* bG1 = Bm + (size_t)(n0 + mS0 + 64) * K + qS * 8;
    short* aL0 = As + (size_t)(w * 64) * 8;
    short* aL1 = As + (size_t)(256 + w * 64) * 8;
    short* bL0 = Bs + (size_t)(w * 64) * 8;
    short* bL1 = Bs + (size_t)(256 + w * 64) * 8;

    int a_off[4], b_off[4];
    #pragma unroll
    for (int i = 0; i < 4; ++i) {
        int am = wm * 64 + i * 16 + l16;
        a_off[i] = (am * 4 + (quad ^ ((am >> 1) & 3))) * 8;
        int bn = wn * 64 + i * 16 + l16;
        b_off[i] = (bn * 4 + (quad ^ ((bn >> 1) & 3))) * 8;
    }

    f32x4 acc[4][4];
    const f32x4 zero4 = {0.f, 0.f, 0.f, 0.f};
    #pragma unroll
    for (int i = 0; i < 4; ++i)
        #pragma unroll
        for (int j = 0; j < 4; ++j) acc[i][j] = zero4;

    for (int k0 = 0; k0 < K; k0 += BK) {
        __syncthreads();
        load_lds16(aG0 + k0, aL0);
        load_lds16(aG1 + k0, aL1);
        load_lds16(bG0 + k0, bL0);
        load_lds16(bG1 + k0, bL1);
        __syncthreads();

        short8 af[4], bf[4];
        #pragma unroll
        for (int i = 0; i < 4; ++i) {
            af[i] = *(const short8*)(As + a_off[i]);
            bf[i] = *(const short8*)(Bs + b_off[i]);
        }
        #pragma unroll
        for (int i = 0; i < 4; ++i)
            #pragma unroll
            for (int j = 0; j < 4; ++j)
                acc[i][j] = __builtin_amdgcn_mfma_f32_16x16x32_bf16(
                    af[i], bf[j], acc[i][j], 0, 0, 0);
    }

    // ---- epilogue: C/D layout col=l16, row=quad*4+reg ---------------------
    if (MODE == 0) {
        #pragma unroll
        for (int i = 0; i < 4; ++i) {
            const int row_base = m0 + wm * 64 + i * 16 + quad * 4;
            #pragma unroll
            for (int j = 0; j < 4; ++j) {
                const int col = n0 + wn * 64 + j * 16 + l16;
                #pragma unroll
                for (int r = 0; r < 4; ++r)
                    Cf[(size_t)(row_base + r) * N + col] = acc[i][j][r];
            }
        }
    } else {
        const int region = n0 >> 10;                 // 0=Q, 1=K, 2=V
        if (region < 2) {
            short* dst = (region == 0) ? Qp : Kp;
            const float sc = (region == 0) ? qscale : 1.0f;
            #pragma unroll
            for (int i = 0; i < 4; ++i) {
                const int row_base = m0 + wm * 64 + i * 16 + quad * 4;
                #pragma unroll
                for (int j = 0; j < 4; ++j) {
                    const int colw = (n0 & 1023) + wn * 64 + j * 16 + l16;
                    #pragma unroll
                    for (int r = 0; r < 4; ++r)
                        dst[(size_t)(row_base + r) * C_DIM + colw] =
                            f2bf(acc[i][j][r] * sc);
                }
            }
        } else {
            // V: store transposed to Vt[B*NH][HS][T]; 4 consecutive t per lane
            #pragma unroll
            for (int i = 0; i < 4; ++i) {
                const int row_base = m0 + wm * 64 + i * 16 + quad * 4;
                const int bI = row_base >> 11;       // batch
                const int t0 = row_base & 2047;      // time (4-aligned)
                #pragma unroll
                for (int j = 0; j < 4; ++j) {
                    const int d_full = (n0 - 2048) + wn * 64 + j * 16 + l16;
                    const int head = d_full >> 6;
                    const int d    = d_full & 63;
                    short4v o;
                    o.x = f2bf(acc[i][j][0]); o.y = f2bf(acc[i][j][1]);
                    o.z = f2bf(acc[i][j][2]); o.w = f2bf(acc[i][j][3]);
                    *(short4v*)(Vtp + ((size_t)((bI * NHEAD + head) * HS + d) << 11) + t0) = o;
                }
            }
        }
    }
}

// ---------------------------------------------------------------------------
// Flash attention v5: R6 dataflow (4 waves, QSUB=4, K-row perm, S^T trick,
// no-max softmax) + 2-way KEY SPLIT via blockIdx.z.
// Each block: 256 q-rows x 1024 keys; writes UNNORMALIZED bf16 O-partial and
// fp32 l-partial. Grid 1024 blocks -> 4 blocks/CU (16 waves/CU) with
// unchanged LDS-traffic-per-MFMA (the R7 mistake). Q pre-scaled by
// 0.125*log2e at projection -> inner loop is bare exp2f.
// ---------------------------------------------------------------------------
#define QSUB 4

__global__ __launch_bounds__(256, 4) void attn_mfma5(
    const short* __restrict__ Qb,    // [B,T,C] bf16, pre-scaled
    const short* __restrict__ Kb,    // [B,T,C] bf16
    const short* __restrict__ Vt,    // [B*NH, HS, T] bf16
    short* __restrict__ O0,          // [B,T,C] bf16 partial (z=0)
    short* __restrict__ O1,          // [B,T,C] bf16 partial (z=1)
    float* __restrict__ Lp)          // [2][B*NH][T] fp32 partial sums
{
    const int i0   = blockIdx.x * (64 * QSUB);
    const int head = blockIdx.y;
    const int z    = blockIdx.z;
    const int b = head >> 4, h = head & 15;

    short* __restrict__ Op = z ? O1 : O0;

    const int t    = threadIdx.x;
    const int w    = t >> 6;
    const int lane = t & 63;
    const int l16  = lane & 15;
    const int quad = lane >> 4;

    __shared__ short Ks[64][72];     // [perm key][dim]
    __shared__ short Vts[64][72];    // [dim][key]

    short8 qf[QSUB][2];
    #pragma unroll
    for (int sub = 0; sub < QSUB; ++sub) {
        const short* qrow = Qb
            + ((size_t)(b * T_DIM) + i0 + sub * 64 + w * 16 + l16) * C_DIM + h * HS;
        qf[sub][0] = *(const short8*)(qrow + quad * 8);
        qf[sub][1] = *(const short8*)(qrow + 32 + quad * 8);
    }

    const f32x4 zero4 = {0.f, 0.f, 0.f, 0.f};
    f32x4 oacc[QSUB][4];
    #pragma unroll
    for (int sub = 0; sub < QSUB; ++sub)
        #pragma unroll
        for (int dg = 0; dg < 4; ++dg) oacc[sub][dg] = zero4;
    float l_part[QSUB];
    #pragma unroll
    for (int sub = 0; sub < QSUB; ++sub) l_part[sub] = 0.0f;

    const int sr = t >> 2;                   // staging row 0..63
    const int sc = (t & 3) * 16;             // staging col
    // K LDS row permutation (R5-verified): [h|q:2|c|r:2] -> [h|c|q:2|r:2]
    const int krow = (sr & 32) | ((sr & 4) << 2) | ((sr & 24) >> 1) | (sr & 3);
    const short* kgbase = Kb + (size_t)(b * T_DIM) * C_DIM + h * HS;
    const short* vgbase = Vt + ((size_t)head * HS + sr) * T_DIM;

    const int jbeg = z * (T_DIM / 2), jend = jbeg + T_DIM / 2;
    for (int j0 = jbeg; j0 < jend; j0 += 64) {
        __syncthreads();                     // prev tile's LDS reads done
        {
            const short* kp = kgbase + (size_t)(j0 + sr) * C_DIM + sc;
            *(short8*)&Ks[krow][sc]     = *(const short8*)kp;
            *(short8*)&Ks[krow][sc + 8] = *(const short8*)(kp + 8);
            const short* vp = vgbase + j0 + sc;
            *(short8*)&Vts[sr][sc]      = *(const short8*)vp;
            *(short8*)&Vts[sr][sc + 8]  = *(const short8*)(vp + 8);
        }
        __syncthreads();

        // K/V MFMA fragments: read once, reuse for all 4 q-subtiles
        short8 ka[4][2], va[4][2];
        #pragma unroll
        for (int kt = 0; kt < 4; ++kt) {
            ka[kt][0] = *(const short8*)&Ks[kt * 16 + l16][quad * 8];
            ka[kt][1] = *(const short8*)&Ks[kt * 16 + l16][32 + quad * 8];
            va[kt][0] = *(const short8*)&Vts[kt * 16 + l16][quad * 8];
            va[kt][1] = *(const short8*)&Vts[kt * 16 + l16][32 + quad * 8];
        }

        #pragma unroll
        for (int sub = 0; sub < QSUB; ++sub) {
            f32x4 s[4];
            #pragma unroll
            for (int kt = 0; kt < 4; ++kt) {
                f32x4 acc = zero4;
                acc = __builtin_amdgcn_mfma_f32_16x16x32_bf16(ka[kt][0], qf[sub][0], acc, 0, 0, 0);
                acc = __builtin_amdgcn_mfma_f32_16x16x32_bf16(ka[kt][1], qf[sub][1], acc, 0, 0, 0);
                s[kt] = acc;
            }

            short8 pa[2];
            float lp = l_part[sub];
            #pragma unroll
            for (int hh = 0; hh < 2; ++hh) {
                #pragma unroll
                for (int c = 0; c < 2; ++c) {
                    f32x4 sv = s[2 * hh + c];
                    #pragma unroll
                    for (int r = 0; r < 4; ++r) {
                        float p = exp2f(sv[r]);      // scale pre-folded into Q
                        lp += p;
                        pa[hh][c * 4 + r] = f2bf(p);
                    }
                }
            }
            l_part[sub] = lp;

            #pragma unroll
            for (int dg = 0; dg < 4; ++dg) {
                oacc[sub][dg] = __builtin_amdgcn_mfma_f32_16x16x32_bf16(pa[0], va[dg][0], oacc[sub][dg], 0, 0, 0);
                oacc[sub][dg] = __builtin_amdgcn_mfma_f32_16x16x32_bf16(pa[1], va[dg][1], oacc[sub][dg], 0, 0, 0);
            }
        }
    }

    #pragma unroll
    for (int sub = 0; sub < QSUB; ++sub) {
        float lp = l_part[sub];
        lp += __shfl_xor(lp, 16);
        lp += __shfl_xor(lp, 32);
        if (quad == 0)   // lanes 0..15 hold l for q = i0+sub*64+w*16+l16
            Lp[((size_t)(z * B_DIM * NHEAD + head) << 11) + i0 + sub * 64 + w * 16 + l16] = lp;

        #pragma unroll
        for (int r = 0; r < 4; ++r) {
            short* orow = Op + ((size_t)(b * T_DIM) + i0 + sub * 64 + w * 16 + quad * 4 + r) * C_DIM + h * HS;
            #pragma unroll
            for (int dg = 0; dg < 4; ++dg)
                orow[dg * 16 + l16] = f2bf(oacc[sub][dg][r]);   // unnormalized
        }
    }
}

// ---------------------------------------------------------------------------
// Combine partials: Ob[i] = (O0[i] + O1[i]) / (l0 + l1). Elementwise; Ob
// aliases O0 (safe). 8 bf16 per thread.
// ---------------------------------------------------------------------------
__global__ __launch_bounds__(256) void combine_o(
    const short* __restrict__ O1,
    const float* __restrict__ Lp,
    short* __restrict__ O0_and_out, int n8)
{
    int i = blockIdx.x * 256 + threadIdx.x;
    if (i >= n8) return;
    const int row  = i >> 7;                 // 128 groups of 8 per row
    const int cg   = i & 127;
    const int bI   = row >> 11;
    const int tI   = row & 2047;
    const int head = cg >> 3;
    const size_t lidx = ((size_t)(bI * NHEAD + head) << 11) + tI;
    const float linv = 1.0f / (Lp[lidx] + Lp[lidx + ((size_t)B_DIM * NHEAD << 11)]);

    short8 a = *((const short8*)O0_and_out + i);
    short8 c = *((const short8*)O1 + i);
    short8 o;
    #pragma unroll
    for (int e = 0; e < 8; ++e)
        o[e] = f2bf((b2f(a[e]) + b2f(c[e])) * linv);
    *((short8*)O0_and_out + i) = o;
}

// ---------------------------------------------------------------------------
// ws layout (bytes), NB = 2*M*C = 16.8MB, WB = 2*C*C = 2.1MB:
//   [0]         xb bf16           (dead after QKV gemm -> O-partial z=1)
//   [NB]        Qb bf16 [M,C]     (pre-scaled by QSCALE)
//   [2NB]       Kb bf16 [M,C]
//   [3NB]       Vt bf16 [B*NH,HS,T]   (written transposed by QKV gemm)
//   [4NB]       W3b (3*WB) | Wob (WB)
//   [4NB+4WB]   O-partial z=0 / combined Ob bf16 [M,C]
//   [5NB+4WB]   Lp fp32 [2][B*NH][T]  (1MB)            total ~93.4MB
// ---------------------------------------------------------------------------
extern "C" void kernel_launch(void* const* d_in, const int* in_sizes, int n_in,
                              void* d_out, int out_size, void* d_ws, size_t ws_size,
                              hipStream_t stream) {
    const float* x  = (const float*)d_in[0];
    const float* Wk = (const float*)d_in[1];
    const float* Wq = (const float*)d_in[2];
    const float* Wv = (const float*)d_in[3];
    const float* Wo = (const float*)d_in[4];
    float* out = (float*)d_out;

    const int M = B_DIM * T_DIM;                       // 8192
    const size_t NE = (size_t)M * C_DIM;               // 8.4M elements
    const size_t NB = 2 * NE;                          // bytes
    const size_t WB = (size_t)2 * C_DIM * C_DIM;
    const size_t WE = (size_t)C_DIM * C_DIM;

    char* ws = (char*)d_ws;
    short* xb  = (short*)(ws);
    short* Op1 = xb;                                   // reuse after QKV gemm
    short* Qb  = (short*)(ws + 1 * NB);
    short* Kb  = (short*)(ws + 2 * NB);
    short* Vtb = (short*)(ws + 3 * NB);
    short* W3b = (short*)(ws + 4 * NB);
    short* Wob = (short*)(ws + 4 * NB + 3 * WB);
    short* Op0 = (short*)(ws + 4 * NB + 4 * WB);       // also combined Ob
    float* Lp  = (float*)(ws + 5 * NB + 4 * WB);

    // all input casts in one launch
    cast_all<<<dim3((int)(NE / 8 / 256), 5), 256, 0, stream>>>(
        x, Wq, Wk, Wv, Wo, xb, W3b, Wob, (int)(NE / 8), (int)(WE / 8));

    // fused QKV projection with split/scaled/transposed epilogue
    gemm_bt_mfma<2><<<dim3(3 * C_DIM / BN, M / BM), 256, 0, stream>>>(
        xb, W3b, nullptr, Qb, Kb, Vtb, M, 3 * C_DIM, C_DIM, QSCALE);

    // attention, 2-way key split
    attn_mfma5<<<dim3(T_DIM / (64 * QSUB), B_DIM * NHEAD, 2), 256, 0, stream>>>(
        Qb, Kb, Vtb, Op0, Op1, Lp);

    // combine partials (writes into Op0)
    combine_o<<<(int)(NE / 8 / 256), 256, 0, stream>>>(
        Op1, Lp, Op0, (int)(NE / 8));

    // output projection (fp32 out)
    gemm_bt_mfma<0><<<dim3(C_DIM / BN, M / BM), 256, 0, stream>>>(
        Op0, Wob, out, nullptr, nullptr, nullptr, M, C_DIM, C_DIM, 1.0f);
}